// Round 9
// baseline (521.322 us; speedup 1.0000x reference)
//
#include <hip/hip_runtime.h>
#include <hip/hip_bf16.h>
#include <stdint.h>

typedef short bf16x8 __attribute__((ext_vector_type(8)));
typedef float f32x4 __attribute__((ext_vector_type(4)));
typedef unsigned int u32x2 __attribute__((ext_vector_type(2)));

__device__ __forceinline__ uint32_t pack2f(float lo, float hi) {
  union { __hip_bfloat162 h; uint32_t u; } c;
  c.h.x = __float2bfloat16(lo);
  c.h.y = __float2bfloat16(hi);
  return c.u;
}

__device__ __forceinline__ unsigned short f32_to_bf16(float f) {
  union { __hip_bfloat16 h; unsigned short u; } c;
  c.h = __float2bfloat16(f);
  return c.u;
}

__device__ __forceinline__ float fast_tanh(float x) {
  float e = __builtin_amdgcn_exp2f(x * 2.8853900817779268f);
  return 1.0f - 2.0f * __builtin_amdgcn_rcpf(e + 1.0f);
}

#define GLD16(g, l)                                                                    \
  __builtin_amdgcn_global_load_lds((const __attribute__((address_space(1))) void*)(g), \
                                   (__attribute__((address_space(3))) void*)(l), 16, 0, 0)

#define MFMA16(a, b, c) __builtin_amdgcn_mfma_f32_16x16x32_bf16(a, b, c, 0, 0, 0)
#define SBAR0() __builtin_amdgcn_sched_barrier(0)

// ---------------- W1k transpose + bf16 convert: W1kt[j][k] = bf16(W1[1024+k][j]) ----------------
__global__ void transpose_w1k(const float* __restrict__ W1, unsigned short* __restrict__ W1kt) {
  __shared__ float t[64][65];
  const int kb = blockIdx.x * 64;
  const int jb = blockIdx.y * 64;
  const int c = threadIdx.x & 63;
  const int r = threadIdx.x >> 6;  // 0..3
#pragma unroll
  for (int i = 0; i < 16; ++i) {
    const int k = i * 4 + r;
    t[k][c] = W1[(size_t)(1024 + kb + k) * 1024 + (jb + c)];
  }
  __syncthreads();
#pragma unroll
  for (int i = 0; i < 16; ++i) {
    const int j = i * 4 + r;
    W1kt[(size_t)(jb + j) * 1024 + (kb + c)] = f32_to_bf16(t[c][j]);
  }
}

// ---------------- convert keys -> bf16 tiled: keysbf[mt][kt][r 128][k 32] ----------------
__global__ void convert_keys(const float* __restrict__ keys, unsigned short* __restrict__ keysbf) {
  const int mt = blockIdx.x >> 3;   // 0..255 (128-row tiles)
  const int ktg = blockIdx.x & 7;   // kt group of 4
  const int t = threadIdx.x;        // 256
  const int u = t & 7;              // 16B-of-fp32 unit within 128B row-segment
  const int rb = t >> 3;            // 0..31
#pragma unroll
  for (int kk = 0; kk < 4; ++kk) {
    const int kt = ktg * 4 + kk;
#pragma unroll
    for (int p = 0; p < 4; ++p) {
      const int r = rb + p * 32;
      f32x4 v = *(const f32x4*)(keys + (size_t)(mt * 128 + r) * 1024 + kt * 32 + u * 4);
      u32x2 w;
      w.x = pack2f(v.x, v.y);
      w.y = pack2f(v.z, v.w);
      *(u32x2*)(keysbf + ((size_t)(mt * 32 + kt) * 128 + r) * 32 + u * 4) = w;
    }
  }
}

// ---------------- qterm[b][j] = b1[j] + sum_k query[b][k]*W1[k][j] ----------------
__global__ void qterm_kernel(const float* __restrict__ query, const float* __restrict__ W1,
                             const float* __restrict__ b1, float* __restrict__ qterm) {
  const int b = blockIdx.y;
  const int j = blockIdx.x * 64 + (threadIdx.x & 63);
  const int kq = threadIdx.x >> 6;  // 0..3
  __shared__ float part[4][64];
  const float* q = query + b * 1024 + kq * 256;
  const float* wp = W1 + (size_t)(kq * 256) * 1024 + j;
  float acc = 0.f;
#pragma unroll 8
  for (int k = 0; k < 256; ++k) acc += q[k] * wp[(size_t)k * 1024];
  part[kq][threadIdx.x & 63] = acc;
  __syncthreads();
  if (threadIdx.x < 64) {
    const int jj = blockIdx.x * 64 + threadIdx.x;
    qterm[b * 1024 + jj] = b1[jj] + part[0][threadIdx.x] + part[1][threadIdx.x] +
                           part[2][threadIdx.x] + part[3][threadIdx.x];
  }
}

// ================= FAST-PATH GEMM: BM=128 BN=256 BK=32, both operands GLD16 =================
// 512 thr / 8 waves (2 wm x 4 wn of 64x64). A from tiled keysbf (contiguous 8KB/kt-tile),
// B from W1kt. Double-buffered, ONE barrier per kt; stage(t+1) issued before compute(t)
// so the vmcnt(0) drain at the barrier waits on loads a full compute phase old.
// 64B LDS rows -> fragment ds_read_b128 naturally bank-balanced (<=2-way, free). No swizzle.

#define V9_STAGE(kt_, Ad, Bd)                                                       \
  {                                                                                 \
    GLD16(gAsrc + (size_t)(kt_) * 4096, (Ad) + tid * 16);                           \
    _Pragma("unroll") for (int i = 0; i < 2; ++i) {                                 \
      const int c = (i * 512 + tid) >> 2;                                           \
      const int k2 = tid & 3;                                                       \
      GLD16(W1kt + (size_t)(col0 + c) * 1024 + (kt_) * 32 + k2 * 8,                 \
            (Bd) + (i * 512 + tid) * 16);                                           \
    }                                                                               \
  }

#define V9_COMPUTE(Ab, Bb)                                                          \
  {                                                                                 \
    bf16x8 af[4], bv[4];                                                            \
    _Pragma("unroll") for (int mf = 0; mf < 4; ++mf)                                \
        af[mf] = *(const bf16x8*)((Ab) + (wm * 64 + mf * 16 + c16) * 64 + q4 * 16); \
    _Pragma("unroll") for (int nf = 0; nf < 4; ++nf)                                \
        bv[nf] = *(const bf16x8*)((Bb) + (wn * 64 + nf * 16 + c16) * 64 + q4 * 16); \
    _Pragma("unroll") for (int nf = 0; nf < 4; ++nf)                                \
        _Pragma("unroll") for (int mf = 0; mf < 4; ++mf) acc[mf][nf] =              \
            MFMA16(af[mf], bv[nf], acc[mf][nf]);                                    \
  }

#define V9_ITER(kt_, Ac, Bc, An, Bn)                              \
  if ((kt_) < 31) { V9_STAGE((kt_) + 1, An, Bn); }                \
  SBAR0();                                                        \
  V9_COMPUTE(Ac, Bc);                                             \
  SBAR0();                                                        \
  asm volatile("s_waitcnt vmcnt(0) lgkmcnt(0)" ::: "memory");     \
  __builtin_amdgcn_s_barrier();

__global__ __launch_bounds__(512, 6) void gemm_score_v9(
    const unsigned short* __restrict__ keysbf, const unsigned short* __restrict__ W1kt,
    const float* __restrict__ qterm, const float* __restrict__ coverage,
    const float* __restrict__ W1, const float* __restrict__ W2,
    float* __restrict__ scores_part) {
  __shared__ __align__(16) unsigned char lds[51200];
  unsigned char* A0 = lds;              // 8KB
  unsigned char* A1 = lds + 8192;       // 8KB
  unsigned char* B0 = lds + 16384;      // 16KB
  unsigned char* B1 = lds + 32768;      // 16KB
  float* Sred = (float*)(lds + 49152);  // 8 x 64 f32

  const int tid = threadIdx.x;
  const int bid = blockIdx.x;  // 1024
  // bijective XCD clustering: xcd gets rowtiles [32x,32x+32), all 4 colgrps
  const int xcd = bid & 7;
  const int idx = bid >> 3;                 // 0..127
  const int rowt = xcd * 32 + (idx >> 2);   // 0..255
  const int colgrp = idx & 3;               // 0..3
  const int row0 = rowt * 128;
  const int col0 = colgrp * 256;
  const int b = row0 >> 11;
  const int w = tid >> 6;
  const int wm = w >> 2, wn = w & 3;
  const int lane = tid & 63;
  const int c16 = lane & 15, q4 = lane >> 4;

  const unsigned short* gAsrc = keysbf + (size_t)(rowt * 32) * 4096 + tid * 8;

  f32x4 acc[4][4];  // [mf][nf]
  const f32x4 zz = {0.f, 0.f, 0.f, 0.f};
#pragma unroll
  for (int mf = 0; mf < 4; ++mf)
#pragma unroll
    for (int nf = 0; nf < 4; ++nf) acc[mf][nf] = zz;

  // prologue
  V9_STAGE(0, A0, B0);
  asm volatile("s_waitcnt vmcnt(0)" ::: "memory");
  __builtin_amdgcn_s_barrier();

#pragma unroll 1
  for (int th = 0; th < 16; ++th) {
    const int t0 = th * 2, t1 = th * 2 + 1;
    V9_ITER(t0, A0, B0, A1, B1);
    V9_ITER(t1, A1, B1, A0, B0);
  }

  // ---- epilogue: v = acc + qterm + cov*W1c; p_part = sum_cols tanh(v)*W2 ----
  float covv[4][4];
#pragma unroll
  for (int mf = 0; mf < 4; ++mf)
#pragma unroll
    for (int r = 0; r < 4; ++r)
      covv[mf][r] = coverage[row0 + wm * 64 + mf * 16 + q4 * 4 + r];

  float p_part[4][4];
#pragma unroll
  for (int mf = 0; mf < 4; ++mf)
#pragma unroll
    for (int r = 0; r < 4; ++r) p_part[mf][r] = 0.f;

#pragma unroll
  for (int nf = 0; nf < 4; ++nf) {
    const int col = col0 + wn * 64 + nf * 16 + c16;
    const float qt = qterm[b * 1024 + col];
    const float w1c = W1[(size_t)2048 * 1024 + col];
    const float w2 = W2[col];
#pragma unroll
    for (int mf = 0; mf < 4; ++mf)
#pragma unroll
      for (int r = 0; r < 4; ++r) {
        float v = acc[mf][nf][r] + qt + covv[mf][r] * w1c;
        p_part[mf][r] += fast_tanh(v) * w2;
      }
  }

#pragma unroll
  for (int mf = 0; mf < 4; ++mf)
#pragma unroll
    for (int r = 0; r < 4; ++r) {
      float p = p_part[mf][r];
      p += __shfl_xor(p, 1);
      p += __shfl_xor(p, 2);
      p += __shfl_xor(p, 4);
      p += __shfl_xor(p, 8);
      if (c16 == 0) Sred[w * 64 + mf * 16 + q4 * 4 + r] = p;
    }
  __syncthreads();
  if (tid < 128) {
    const int wmv = tid >> 6, j = tid & 63;
    float s = Sred[(wmv * 4 + 0) * 64 + j] + Sred[(wmv * 4 + 1) * 64 + j] +
              Sred[(wmv * 4 + 2) * 64 + j] + Sred[(wmv * 4 + 3) * 64 + j];
    scores_part[(size_t)colgrp * 32768 + row0 + tid] = s;
  }
}

// ================= FALLBACK GEMM (round-8, fp32 keys, no extra workspace) =================
#define O8_STAGE_B(t, Bdst)                                       \
  _Pragma("unroll") for (int i = 0; i < 4; ++i) {                 \
    const int r = w * 32 + i * 8 + (lane >> 3);                   \
    const int u = (lane & 7) ^ (r & 7);                           \
    GLD16(W1kt + (((size_t)(col0 + r)) << 10) + (t) * 64 + u * 8, \
          (Bdst) + w * 4096 + lane * 16 + i * 1024);              \
  }

#define O8_LOAD_A(t)                            \
  _Pragma("unroll") for (int j = 0; j < 8; ++j) \
      Ar[j] = *(const f32x4*)(gA + (t) * 64 + (size_t)j * 16 * 1024);

#define O8_WRITE_A()                                                \
  _Pragma("unroll") for (int j = 0; j < 8; ++j) {                   \
    const int r = arow + j * 16;                                    \
    u32x2 p;                                                        \
    p.x = pack2f(Ar[j].x, Ar[j].y);                                 \
    p.y = pack2f(Ar[j].z, Ar[j].w);                                 \
    *(u32x2*)(Alds + r * 128 + (((aun ^ (r & 7)) << 4) + auh)) = p; \
  }

#define O8_COMPUTE(Bsrc)                                                                 \
  _Pragma("unroll") for (int kk = 0; kk < 2; ++kk) {                                     \
    bf16x8 af[4], bfv[4];                                                                \
    _Pragma("unroll") for (int mf = 0; mf < 4; ++mf) {                                   \
      const int ra = wm * 64 + mf * 16 + c16;                                            \
      af[mf] = *(const bf16x8*)(Alds + ra * 128 + (((kk * 4 + q4) ^ (ra & 7)) << 4));    \
    }                                                                                    \
    _Pragma("unroll") for (int nf = 0; nf < 4; ++nf) {                                   \
      const int ca = wn * 64 + nf * 16 + c16;                                            \
      bfv[nf] = *(const bf16x8*)((Bsrc) + ca * 128 + (((kk * 4 + q4) ^ (ca & 7)) << 4)); \
    }                                                                                    \
    _Pragma("unroll") for (int nf = 0; nf < 4; ++nf)                                     \
        _Pragma("unroll") for (int mf = 0; mf < 4; ++mf) acc[mf][nf] =                   \
            MFMA16(af[mf], bfv[nf], acc[mf][nf]);                                        \
  }

#define O8_DRAIN_BAR()                                        \
  asm volatile("s_waitcnt vmcnt(0) lgkmcnt(0)" ::: "memory"); \
  __builtin_amdgcn_s_barrier();

#define O8_LGKM_BAR()                                \
  asm volatile("s_waitcnt lgkmcnt(0)" ::: "memory"); \
  __builtin_amdgcn_s_barrier();

#define O8_PIPE_ITER(t, Bc, Bn)                 \
  if ((t) < 15) { O8_STAGE_B((t) + 1, Bn); }    \
  SBAR0();                                      \
  O8_COMPUTE(Bc);                               \
  if ((t) < 15) {                               \
    O8_DRAIN_BAR();                             \
    O8_WRITE_A();                               \
    if ((t) < 14) O8_LOAD_A((t) + 2);           \
    O8_LGKM_BAR();                              \
  }

__global__ __launch_bounds__(256, 3) void gemm_score_o8(
    const float* __restrict__ keys, const unsigned short* __restrict__ W1kt,
    const float* __restrict__ qterm, const float* __restrict__ coverage,
    const float* __restrict__ W1, const float* __restrict__ W2,
    float* __restrict__ scores_part) {
  __shared__ __align__(16) unsigned char lds[50176];
  unsigned char* Alds = lds;
  unsigned char* B0 = lds + 16384;
  unsigned char* B1 = lds + 32768;
  float* Sred = (float*)(lds + 49152);

  const int tid = threadIdx.x;
  const int bid = blockIdx.x;
  const int xcd = bid & 7;
  const int idx = bid >> 3;
  const int rowgrp = xcd * 32 + (idx >> 3);
  const int colgrp = idx & 7;
  const int row0 = rowgrp * 128;
  const int col0 = colgrp * 128;
  const int b = row0 >> 11;
  const int w = tid >> 6;
  const int wm = w >> 1, wn = w & 1;
  const int lane = tid & 63;
  const int c16 = lane & 15, q4 = lane >> 4;

  const int arow = tid >> 4;
  const int akf = (tid & 15) * 4;
  const float* gA = keys + (size_t)(row0 + arow) * 1024 + akf;
  const int auh = (tid & 1) * 8;
  const int aun = (tid & 15) >> 1;

  f32x4 acc[4][4];
  const f32x4 zz = {0.f, 0.f, 0.f, 0.f};
#pragma unroll
  for (int mf = 0; mf < 4; ++mf)
#pragma unroll
    for (int nf = 0; nf < 4; ++nf) acc[mf][nf] = zz;

  f32x4 Ar[8];

  O8_LOAD_A(0);
  SBAR0();
  O8_STAGE_B(0, B0);
  SBAR0();
  O8_WRITE_A();
  O8_LOAD_A(1);
  SBAR0();
  asm volatile("s_waitcnt vmcnt(8) lgkmcnt(0)" ::: "memory");
  __builtin_amdgcn_s_barrier();

#pragma unroll 1
  for (int th = 0; th < 8; ++th) {
    const int t0 = th * 2, t1 = th * 2 + 1;
    O8_PIPE_ITER(t0, B0, B1);
    O8_PIPE_ITER(t1, B1, B0);
  }

  float covv[4][4];
#pragma unroll
  for (int mf = 0; mf < 4; ++mf)
#pragma unroll
    for (int r = 0; r < 4; ++r)
      covv[mf][r] = coverage[row0 + wm * 64 + mf * 16 + q4 * 4 + r];

  float p_part[4][4];
#pragma unroll
  for (int mf = 0; mf < 4; ++mf)
#pragma unroll
    for (int r = 0; r < 4; ++r) p_part[mf][r] = 0.f;

#pragma unroll
  for (int nf = 0; nf < 4; ++nf) {
    const int col = col0 + wn * 64 + nf * 16 + c16;
    const float qt = qterm[b * 1024 + col];
    const float w1c = W1[(size_t)2048 * 1024 + col];
    const float w2 = W2[col];
#pragma unroll
    for (int mf = 0; mf < 4; ++mf)
#pragma unroll
      for (int r = 0; r < 4; ++r) {
        float v = acc[mf][nf][r] + qt + covv[mf][r] * w1c;
        p_part[mf][r] += fast_tanh(v) * w2;
      }
  }

#pragma unroll
  for (int mf = 0; mf < 4; ++mf)
#pragma unroll
    for (int r = 0; r < 4; ++r) {
      float p = p_part[mf][r];
      p += __shfl_xor(p, 1);
      p += __shfl_xor(p, 2);
      p += __shfl_xor(p, 4);
      p += __shfl_xor(p, 8);
      if (c16 == 0) Sred[w * 64 + mf * 16 + q4 * 4 + r] = p;
    }
  __syncthreads();
  if (tid < 128) {
    const int wmv = tid >> 6, j = tid & 63;
    float s = Sred[wmv * 128 + j] + Sred[wmv * 128 + 64 + j];
    scores_part[(size_t)colgrp * 32768 + row0 + tid] = s;
  }
}

// ---------------- softmax over L per batch (sums ngroups partials) ----------------
__global__ void softmax_kernel(const float* __restrict__ sp, float* __restrict__ att,
                               int ngroups) {
  const int b = blockIdx.x;
  const int tid = threadIdx.x;
  float* a = att + b * 2048;
  __shared__ float red[4];
  float mx = -1e30f;
  for (int l = tid; l < 2048; l += 256) {
    float v = 0.f;
    for (int g = 0; g < ngroups; ++g) v += sp[(size_t)g * 32768 + b * 2048 + l];
    a[l] = v;
    mx = fmaxf(mx, v);
  }
#pragma unroll
  for (int o = 1; o < 64; o <<= 1) mx = fmaxf(mx, __shfl_xor(mx, o));
  if ((tid & 63) == 0) red[tid >> 6] = mx;
  __syncthreads();
  mx = fmaxf(fmaxf(red[0], red[1]), fmaxf(red[2], red[3]));
  __syncthreads();
  float sum = 0.f;
  for (int l = tid; l < 2048; l += 256) {
    float e = __expf(a[l] - mx);
    a[l] = e;
    sum += e;
  }
#pragma unroll
  for (int o = 1; o < 64; o <<= 1) sum += __shfl_xor(sum, o);
  if ((tid & 63) == 0) red[tid >> 6] = sum;
  __syncthreads();
  sum = red[0] + red[1] + red[2] + red[3];
  const float inv = 1.0f / sum;
  for (int l = tid; l < 2048; l += 256) a[l] *= inv;
}

// ---------------- ctx_part[sl][b][j] = sum over 128 rows of att*keys ----------------
__global__ void ctxpre_kernel(const float* __restrict__ keys, const float* __restrict__ att,
                              float* __restrict__ ctx_part) {
  const int b = blockIdx.x;     // 16
  const int sl = blockIdx.y;    // 16 slices of 128 rows
  const int tid = threadIdx.x;  // 256
  const float* ab = att + b * 2048 + sl * 128;
  const f32x4* kp = (const f32x4*)(keys + ((size_t)b * 2048 + sl * 128) * 1024) + tid;
  f32x4 acc = {0.f, 0.f, 0.f, 0.f};
#pragma unroll 4
  for (int l = 0; l < 128; ++l) acc += kp[(size_t)l * 256] * ab[l];
  *(f32x4*)(ctx_part + ((size_t)(sl * 16 + b)) * 1024 + tid * 4) = acc;
}

// ---------------- ctx_pre[b][j] = sum_sl ctx_part[sl][b][j] ----------------
__global__ void ctxreduce_kernel(const float* __restrict__ ctx_part, float* __restrict__ ctx_pre) {
  const int i = blockIdx.x * 256 + threadIdx.x;
  const int b = i >> 10, j = i & 1023;
  float s = 0.f;
#pragma unroll
  for (int sl = 0; sl < 16; ++sl) s += ctx_part[((size_t)(sl * 16 + b)) * 1024 + j];
  ctx_pre[i] = s;
}

// ---------------- context[b][h] = sum_j ctx_pre[b][j] * Wr[j][h] ----------------
__global__ void context_kernel(const float* __restrict__ ctx_pre, const float* __restrict__ Wr,
                               float* __restrict__ out) {
  const int b = blockIdx.y;
  const int h = blockIdx.x * 64 + (threadIdx.x & 63);
  const int jq = threadIdx.x >> 6;
  __shared__ float part[4][64];
  const float* cp = ctx_pre + b * 1024 + jq * 256;
  const float* wp = Wr + (size_t)(jq * 256) * 512 + h;
  float acc = 0.f;
#pragma unroll 8
  for (int k = 0; k < 256; ++k) acc += cp[k] * wp[(size_t)k * 512];
  part[jq][threadIdx.x & 63] = acc;
  __syncthreads();
  if (threadIdx.x < 64)
    out[b * 512 + blockIdx.x * 64 + threadIdx.x] = part[0][threadIdx.x] + part[1][threadIdx.x] +
                                                   part[2][threadIdx.x] + part[3][threadIdx.x];
}

extern "C" void kernel_launch(void* const* d_in, const int* in_sizes, int n_in, void* d_out,
                              int out_size, void* d_ws, size_t ws_size, hipStream_t stream) {
  const float* query = (const float*)d_in[0];     // (16,1,1024)
  const float* keys = (const float*)d_in[1];      // (16,2048,1024)
  const float* coverage = (const float*)d_in[2];  // (16,2048,1)
  const float* W1 = (const float*)d_in[3];        // (2049,1024)
  const float* b1 = (const float*)d_in[4];        // (1024,)
  const float* W2 = (const float*)d_in[5];        // (1024,1)
  const float* Wr = (const float*)d_in[6];        // (1024,512)
  float* out = (float*)d_out;
  char* ws = (char*)d_ws;

  float* scores_part = (float*)ws;          // up to 8*32768 f32 = 1MB @ 0
  float* ctx_part = (float*)ws;             // 1MB, aliases scores_part (dead after softmax)
  float* ctx_pre = (float*)(ws + 1048576);  // 16384 f32
  float* qterm = (float*)(ws + 1114112);    // 16384 f32
  unsigned short* W1kt = (unsigned short*)(ws + 1179648);    // 1M bf16 (2MB)
  unsigned short* keysbf = (unsigned short*)(ws + 3276800);  // 32M bf16 (64MB), fast path only

  const bool fast = ws_size >= (size_t)70500000;

  float* context_out = out;     // 16*512
  float* att_out = out + 8192;  // 16*2048

  transpose_w1k<<<dim3(16, 16), dim3(256), 0, stream>>>(W1, W1kt);
  qterm_kernel<<<dim3(16, 16), dim3(256), 0, stream>>>(query, W1, b1, qterm);
  if (fast) {
    convert_keys<<<dim3(2048), dim3(256), 0, stream>>>(keys, keysbf);
    gemm_score_v9<<<dim3(1024), dim3(512), 0, stream>>>(keysbf, W1kt, qterm, coverage, W1, W2,
                                                        scores_part);
    softmax_kernel<<<dim3(16), dim3(256), 0, stream>>>(scores_part, att_out, 4);
  } else {
    gemm_score_o8<<<dim3(2048), dim3(256), 0, stream>>>(keys, W1kt, qterm, coverage, W1, W2,
                                                        scores_part);
    softmax_kernel<<<dim3(16), dim3(256), 0, stream>>>(scores_part, att_out, 8);
  }
  ctxpre_kernel<<<dim3(16, 16), dim3(256), 0, stream>>>(keys, att_out, ctx_part);
  ctxreduce_kernel<<<dim3(64), dim3(256), 0, stream>>>(ctx_part, ctx_pre);
  context_kernel<<<dim3(8, 16), dim3(256), 0, stream>>>(ctx_pre, Wr, context_out);
}

// Round 10
// 173.855 us; speedup vs baseline: 2.9986x; 2.9986x over previous
//
#include <hip/hip_runtime.h>
#include <hip/hip_bf16.h>
#include <stdint.h>

typedef short bf16x8 __attribute__((ext_vector_type(8)));
typedef float f32x4 __attribute__((ext_vector_type(4)));
typedef unsigned int u32x2 __attribute__((ext_vector_type(2)));
typedef unsigned int u32x4 __attribute__((ext_vector_type(4)));

__device__ __forceinline__ uint32_t pack2f(float lo, float hi) {
  union { __hip_bfloat162 h; uint32_t u; } c;
  c.h.x = __float2bfloat16(lo);
  c.h.y = __float2bfloat16(hi);
  return c.u;
}

__device__ __forceinline__ unsigned short f32_to_bf16(float f) {
  union { __hip_bfloat16 h; unsigned short u; } c;
  c.h = __float2bfloat16(f);
  return c.u;
}

__device__ __forceinline__ float fast_tanh(float x) {
  float e = __builtin_amdgcn_exp2f(x * 2.8853900817779268f);
  return 1.0f - 2.0f * __builtin_amdgcn_rcpf(e + 1.0f);
}

#define GLD16(g, l)                                                                    \
  __builtin_amdgcn_global_load_lds((const __attribute__((address_space(1))) void*)(g), \
                                   (__attribute__((address_space(3))) void*)(l), 16, 0, 0)

#define MFMA16(a, b, c) __builtin_amdgcn_mfma_f32_16x16x32_bf16(a, b, c, 0, 0, 0)
#define SBAR0() __builtin_amdgcn_sched_barrier(0)

// ---------------- W1k transpose + bf16 convert: W1kt[j][k] = bf16(W1[1024+k][j]) ----------------
__global__ void transpose_w1k(const float* __restrict__ W1, unsigned short* __restrict__ W1kt) {
  __shared__ float t[64][65];
  const int kb = blockIdx.x * 64;
  const int jb = blockIdx.y * 64;
  const int c = threadIdx.x & 63;
  const int r = threadIdx.x >> 6;  // 0..3
#pragma unroll
  for (int i = 0; i < 16; ++i) {
    const int k = i * 4 + r;
    t[k][c] = W1[(size_t)(1024 + kb + k) * 1024 + (jb + c)];
  }
  __syncthreads();
#pragma unroll
  for (int i = 0; i < 16; ++i) {
    const int j = i * 4 + r;
    W1kt[(size_t)(jb + j) * 1024 + (kb + c)] = f32_to_bf16(t[c][j]);
  }
}

// ---------------- convert keys -> bf16 row-major ----------------
__global__ void convert_keys(const float* __restrict__ keys, unsigned short* __restrict__ keysbf) {
  const int bid = blockIdx.x, tid = threadIdx.x;
#pragma unroll
  for (int it = 0; it < 2; ++it) {
    const size_t c8 = ((size_t)bid * 512 + it * 256 + tid) * 8;
    f32x4 a = *(const f32x4*)(keys + c8);
    f32x4 b = *(const f32x4*)(keys + c8 + 4);
    u32x4 p;
    p.x = pack2f(a.x, a.y);
    p.y = pack2f(a.z, a.w);
    p.z = pack2f(b.x, b.y);
    p.w = pack2f(b.z, b.w);
    *(u32x4*)(keysbf + c8) = p;
  }
}

// ---------------- qterm[b][j] = b1[j] + sum_k query[b][k]*W1[k][j] ----------------
__global__ void qterm_kernel(const float* __restrict__ query, const float* __restrict__ W1,
                             const float* __restrict__ b1, float* __restrict__ qterm) {
  const int b = blockIdx.y;
  const int j = blockIdx.x * 64 + (threadIdx.x & 63);
  const int kq = threadIdx.x >> 6;  // 0..3
  __shared__ float part[4][64];
  const float* q = query + b * 1024 + kq * 256;
  const float* wp = W1 + (size_t)(kq * 256) * 1024 + j;
  float acc = 0.f;
#pragma unroll 8
  for (int k = 0; k < 256; ++k) acc += q[k] * wp[(size_t)k * 1024];
  part[kq][threadIdx.x & 63] = acc;
  __syncthreads();
  if (threadIdx.x < 64) {
    const int jj = blockIdx.x * 64 + threadIdx.x;
    qterm[b * 1024 + jj] = b1[jj] + part[0][threadIdx.x] + part[1][threadIdx.x] +
                           part[2][threadIdx.x] + part[3][threadIdx.x];
  }
}

// ---------------- fused GEMM + tanh + W2-reduce (o10: all-GLD, 1 barrier/kt) ----------------
// 256 thr / 4 waves (2x2 of 64x64), tile 128x128, BK=64, 16 k-tiles, grid 2048.
// BOTH operands bf16, staged via global_load_lds with XOR fold in the global src
// (LDS dest linear). One barrier per kt; the 8 staged GLDs are a full compute
// phase old at the vmcnt(0) drain. LDS 66.5KB -> 2 blocks/CU (8 waves/CU).
// bf16 A shrinks per-XCD resident set to ~4MB (fits L2; fp32 A thrashed at 6MB).

// stage a [128 rows][64 k] bf16 tile from row-major src (row stride 1024 elems)
#define STAGE_T(t_, src, Dd)                                \
  _Pragma("unroll") for (int i = 0; i < 4; ++i) {           \
    const int r = w * 32 + i * 8 + (lane >> 3);             \
    const int u = (lane & 7) ^ (r & 7);                     \
    GLD16((src) + (((size_t)r) << 10) + (t_) * 64 + u * 8,  \
          (Dd) + w * 4096 + lane * 16 + i * 1024);          \
  }

#define O10_COMPUTE(Asrc, Bsrc)                                                          \
  _Pragma("unroll") for (int kk = 0; kk < 2; ++kk) {                                     \
    bf16x8 af[4], bfv[4];                                                                \
    _Pragma("unroll") for (int mf = 0; mf < 4; ++mf) {                                   \
      const int ra = wm * 64 + mf * 16 + c16;                                            \
      af[mf] = *(const bf16x8*)((Asrc) + ra * 128 + (((kk * 4 + q4) ^ (ra & 7)) << 4));  \
    }                                                                                    \
    _Pragma("unroll") for (int nf = 0; nf < 4; ++nf) {                                   \
      const int ca = wn * 64 + nf * 16 + c16;                                            \
      bfv[nf] = *(const bf16x8*)((Bsrc) + ca * 128 + (((kk * 4 + q4) ^ (ca & 7)) << 4)); \
    }                                                                                    \
    _Pragma("unroll") for (int nf = 0; nf < 4; ++nf)                                     \
        _Pragma("unroll") for (int mf = 0; mf < 4; ++mf) acc[mf][nf] =                   \
            MFMA16(af[mf], bfv[nf], acc[mf][nf]);                                        \
  }

#define O10_ITER(t_, Ac, Bc, An, Bn)                          \
  if ((t_) < 15) {                                            \
    STAGE_T((t_) + 1, gAbase, An);                            \
    STAGE_T((t_) + 1, gBbase, Bn);                            \
  }                                                           \
  SBAR0();                                                    \
  O10_COMPUTE(Ac, Bc);                                        \
  SBAR0();                                                    \
  asm volatile("s_waitcnt vmcnt(0) lgkmcnt(0)" ::: "memory"); \
  __builtin_amdgcn_s_barrier();

__global__ __launch_bounds__(256, 2) void gemm_score_o10(
    const unsigned short* __restrict__ keysbf, const unsigned short* __restrict__ W1kt,
    const float* __restrict__ qterm, const float* __restrict__ coverage,
    const float* __restrict__ W1, const float* __restrict__ W2,
    float* __restrict__ scores_part) {
  __shared__ __align__(16) unsigned char lds[66560];
  unsigned char* A0 = lds;
  unsigned char* A1 = lds + 16384;
  unsigned char* B0 = lds + 32768;
  unsigned char* B1 = lds + 49152;
  float* Sred = (float*)(lds + 65536);  // 4 x 64 f32

  const int tid = threadIdx.x;
  const int bid = blockIdx.x;
  // bijective XCD clustering: XCD x handles rowgrps [32x,32x+32), all 8 colgrps
  const int xcd = bid & 7;
  const int idx = bid >> 3;                  // 0..255
  const int rowgrp = xcd * 32 + (idx >> 3);  // 0..255
  const int colgrp = idx & 7;                // 0..7
  const int row0 = rowgrp * 128;
  const int col0 = colgrp * 128;
  const int b = row0 >> 11;
  const int w = tid >> 6;
  const int wm = w >> 1, wn = w & 1;
  const int lane = tid & 63;
  const int c16 = lane & 15, q4 = lane >> 4;

  const unsigned short* gAbase = keysbf + ((size_t)row0 << 10);
  const unsigned short* gBbase = W1kt + ((size_t)col0 << 10);

  f32x4 acc[4][4];  // [mf][nf]
  const f32x4 zz = {0.f, 0.f, 0.f, 0.f};
#pragma unroll
  for (int mf = 0; mf < 4; ++mf)
#pragma unroll
    for (int nf = 0; nf < 4; ++nf) acc[mf][nf] = zz;

  // prologue
  STAGE_T(0, gAbase, A0);
  STAGE_T(0, gBbase, B0);
  asm volatile("s_waitcnt vmcnt(0)" ::: "memory");
  __builtin_amdgcn_s_barrier();

#pragma unroll 1
  for (int th = 0; th < 8; ++th) {
    const int t0 = th * 2, t1 = th * 2 + 1;
    O10_ITER(t0, A0, B0, A1, B1);
    O10_ITER(t1, A1, B1, A0, B0);
  }

  // ---- epilogue: v = acc + qterm + cov*W1c; p_part = sum_cols tanh(v)*W2 ----
  float covv[4][4];
#pragma unroll
  for (int mf = 0; mf < 4; ++mf)
#pragma unroll
    for (int r = 0; r < 4; ++r)
      covv[mf][r] = coverage[row0 + wm * 64 + mf * 16 + q4 * 4 + r];

  float p_part[4][4];
#pragma unroll
  for (int mf = 0; mf < 4; ++mf)
#pragma unroll
    for (int r = 0; r < 4; ++r) p_part[mf][r] = 0.f;

#pragma unroll
  for (int nf = 0; nf < 4; ++nf) {
    const int col = col0 + wn * 64 + nf * 16 + c16;
    const float qt = qterm[b * 1024 + col];
    const float w1c = W1[(size_t)2048 * 1024 + col];
    const float w2 = W2[col];
#pragma unroll
    for (int mf = 0; mf < 4; ++mf)
#pragma unroll
      for (int r = 0; r < 4; ++r) {
        float v = acc[mf][nf][r] + qt + covv[mf][r] * w1c;
        p_part[mf][r] += fast_tanh(v) * w2;
      }
  }

  // reduce over 16 col-lanes, then across waves via Sred
#pragma unroll
  for (int mf = 0; mf < 4; ++mf)
#pragma unroll
    for (int r = 0; r < 4; ++r) {
      float p = p_part[mf][r];
      p += __shfl_xor(p, 1);
      p += __shfl_xor(p, 2);
      p += __shfl_xor(p, 4);
      p += __shfl_xor(p, 8);
      if (c16 == 0) Sred[w * 64 + mf * 16 + q4 * 4 + r] = p;
    }
  __syncthreads();
  if (tid < 128) {
    const int wmv = tid >> 6, j = tid & 63;
    float s = Sred[wmv * 128 + j] + Sred[wmv * 128 + 64 + j];
    scores_part[(size_t)colgrp * 32768 + row0 + tid] = s;
  }
}

// ---------------- softmax over L per batch (sums 8 colgrp partials) ----------------
__global__ void softmax_kernel(const float* __restrict__ sp, float* __restrict__ att) {
  const int b = blockIdx.x;
  const int tid = threadIdx.x;
  float* a = att + b * 2048;
  __shared__ float red[4];
  float mx = -1e30f;
  for (int l = tid; l < 2048; l += 256) {
    float v = 0.f;
#pragma unroll
    for (int g = 0; g < 8; ++g) v += sp[(size_t)g * 32768 + b * 2048 + l];
    a[l] = v;
    mx = fmaxf(mx, v);
  }
#pragma unroll
  for (int o = 1; o < 64; o <<= 1) mx = fmaxf(mx, __shfl_xor(mx, o));
  if ((tid & 63) == 0) red[tid >> 6] = mx;
  __syncthreads();
  mx = fmaxf(fmaxf(red[0], red[1]), fmaxf(red[2], red[3]));
  __syncthreads();
  float sum = 0.f;
  for (int l = tid; l < 2048; l += 256) {
    float e = __expf(a[l] - mx);
    a[l] = e;
    sum += e;
  }
#pragma unroll
  for (int o = 1; o < 64; o <<= 1) sum += __shfl_xor(sum, o);
  if ((tid & 63) == 0) red[tid >> 6] = sum;
  __syncthreads();
  sum = red[0] + red[1] + red[2] + red[3];
  const float inv = 1.0f / sum;
  for (int l = tid; l < 2048; l += 256) a[l] *= inv;
}

// ---------------- ctx_part[sl][b][j] = sum over 128 rows of att*keys ----------------
__global__ void ctxpre_kernel(const float* __restrict__ keys, const float* __restrict__ att,
                              float* __restrict__ ctx_part) {
  const int b = blockIdx.x;     // 16
  const int sl = blockIdx.y;    // 16 slices of 128 rows
  const int tid = threadIdx.x;  // 256
  const float* ab = att + b * 2048 + sl * 128;
  const f32x4* kp = (const f32x4*)(keys + ((size_t)b * 2048 + sl * 128) * 1024) + tid;
  f32x4 acc = {0.f, 0.f, 0.f, 0.f};
#pragma unroll 4
  for (int l = 0; l < 128; ++l) acc += kp[(size_t)l * 256] * ab[l];
  *(f32x4*)(ctx_part + ((size_t)(sl * 16 + b)) * 1024 + tid * 4) = acc;
}

// ---------------- ctx_pre[b][j] = sum_sl ctx_part[sl][b][j] ----------------
__global__ void ctxreduce_kernel(const float* __restrict__ ctx_part, float* __restrict__ ctx_pre) {
  const int i = blockIdx.x * 256 + threadIdx.x;
  const int b = i >> 10, j = i & 1023;
  float s = 0.f;
#pragma unroll
  for (int sl = 0; sl < 16; ++sl) s += ctx_part[((size_t)(sl * 16 + b)) * 1024 + j];
  ctx_pre[i] = s;
}

// ---------------- context[b][h] = sum_j ctx_pre[b][j] * Wr[j][h] ----------------
__global__ void context_kernel(const float* __restrict__ ctx_pre, const float* __restrict__ Wr,
                               float* __restrict__ out) {
  const int b = blockIdx.y;
  const int h = blockIdx.x * 64 + (threadIdx.x & 63);
  const int jq = threadIdx.x >> 6;
  __shared__ float part[4][64];
  const float* cp = ctx_pre + b * 1024 + jq * 256;
  const float* wp = Wr + (size_t)(jq * 256) * 512 + h;
  float acc = 0.f;
#pragma unroll 8
  for (int k = 0; k < 256; ++k) acc += cp[k] * wp[(size_t)k * 512];
  part[jq][threadIdx.x & 63] = acc;
  __syncthreads();
  if (threadIdx.x < 64)
    out[b * 512 + blockIdx.x * 64 + threadIdx.x] = part[0][threadIdx.x] + part[1][threadIdx.x] +
                                                   part[2][threadIdx.x] + part[3][threadIdx.x];
}

extern "C" void kernel_launch(void* const* d_in, const int* in_sizes, int n_in, void* d_out,
                              int out_size, void* d_ws, size_t ws_size, hipStream_t stream) {
  const float* query = (const float*)d_in[0];     // (16,1,1024)
  const float* keys = (const float*)d_in[1];      // (16,2048,1024)
  const float* coverage = (const float*)d_in[2];  // (16,2048,1)
  const float* W1 = (const float*)d_in[3];        // (2049,1024)
  const float* b1 = (const float*)d_in[4];        // (1024,)
  const float* W2 = (const float*)d_in[5];        // (1024,1)
  const float* Wr = (const float*)d_in[6];        // (1024,512)
  float* out = (float*)d_out;
  char* ws = (char*)d_ws;

  float* scores_part = (float*)ws;          // 8*32768 f32 = 1MB @ 0
  float* ctx_part = (float*)ws;             // 1MB, aliases scores_part (dead after softmax)
  float* ctx_pre = (float*)(ws + 1048576);  // 16384 f32
  float* qterm = (float*)(ws + 1114112);    // 16384 f32
  unsigned short* W1kt = (unsigned short*)(ws + 1179648);    // 1M bf16 (2MB)
  unsigned short* keysbf = (unsigned short*)(ws + 3276800);  // 32M bf16 (64MB)
  // ws >= 70.5MB proven in round 9 (fast path executed)

  float* context_out = out;     // 16*512
  float* att_out = out + 8192;  // 16*2048

  transpose_w1k<<<dim3(16, 16), dim3(256), 0, stream>>>(W1, W1kt);
  convert_keys<<<dim3(8192), dim3(256), 0, stream>>>(keys, keysbf);
  qterm_kernel<<<dim3(16, 16), dim3(256), 0, stream>>>(query, W1, b1, qterm);
  gemm_score_o10<<<dim3(2048), dim3(256), 0, stream>>>(keysbf, W1kt, qterm, coverage, W1, W2,
                                                       scores_part);
  softmax_kernel<<<dim3(16), dim3(256), 0, stream>>>(scores_part, att_out);
  ctxpre_kernel<<<dim3(16, 16), dim3(256), 0, stream>>>(keys, att_out, ctx_part);
  ctxreduce_kernel<<<dim3(64), dim3(256), 0, stream>>>(ctx_part, ctx_pre);
  context_kernel<<<dim3(8, 16), dim3(256), 0, stream>>>(ctx_pre, Wr, context_out);
}

// Round 11
// 164.024 us; speedup vs baseline: 3.1783x; 1.0599x over previous
//
#include <hip/hip_runtime.h>
#include <hip/hip_bf16.h>
#include <stdint.h>

typedef short bf16x8 __attribute__((ext_vector_type(8)));
typedef float f32x4 __attribute__((ext_vector_type(4)));
typedef unsigned int u32x2 __attribute__((ext_vector_type(2)));
typedef unsigned int u32x4 __attribute__((ext_vector_type(4)));

__device__ __forceinline__ uint32_t pack2f(float lo, float hi) {
  union { __hip_bfloat162 h; uint32_t u; } c;
  c.h.x = __float2bfloat16(lo);
  c.h.y = __float2bfloat16(hi);
  return c.u;
}

__device__ __forceinline__ unsigned short f32_to_bf16(float f) {
  union { __hip_bfloat16 h; unsigned short u; } c;
  c.h = __float2bfloat16(f);
  return c.u;
}

__device__ __forceinline__ float bfbits_to_f32(uint32_t hi16) {
  union { uint32_t u; float f; } c;
  c.u = hi16 << 16;
  return c.f;
}

__device__ __forceinline__ float fast_tanh(float x) {
  float e = __builtin_amdgcn_exp2f(x * 2.8853900817779268f);
  return 1.0f - 2.0f * __builtin_amdgcn_rcpf(e + 1.0f);
}

#define GLD16(g, l)                                                                    \
  __builtin_amdgcn_global_load_lds((const __attribute__((address_space(1))) void*)(g), \
                                   (__attribute__((address_space(3))) void*)(l), 16, 0, 0)

#define MFMA16(a, b, c) __builtin_amdgcn_mfma_f32_16x16x32_bf16(a, b, c, 0, 0, 0)
#define SBAR0() __builtin_amdgcn_sched_barrier(0)

// ---------------- W1k transpose + bf16 convert: W1kt[j][k] = bf16(W1[1024+k][j]) ----------------
__global__ void transpose_w1k(const float* __restrict__ W1, unsigned short* __restrict__ W1kt) {
  __shared__ float t[64][65];
  const int kb = blockIdx.x * 64;
  const int jb = blockIdx.y * 64;
  const int c = threadIdx.x & 63;
  const int r = threadIdx.x >> 6;  // 0..3
#pragma unroll
  for (int i = 0; i < 16; ++i) {
    const int k = i * 4 + r;
    t[k][c] = W1[(size_t)(1024 + kb + k) * 1024 + (jb + c)];
  }
  __syncthreads();
#pragma unroll
  for (int i = 0; i < 16; ++i) {
    const int j = i * 4 + r;
    W1kt[(size_t)(jb + j) * 1024 + (kb + c)] = f32_to_bf16(t[c][j]);
  }
}

// ---------------- convert keys -> bf16 row-major ----------------
__global__ void convert_keys(const float* __restrict__ keys, unsigned short* __restrict__ keysbf) {
  const int bid = blockIdx.x, tid = threadIdx.x;
#pragma unroll
  for (int it = 0; it < 2; ++it) {
    const size_t c8 = ((size_t)bid * 512 + it * 256 + tid) * 8;
    f32x4 a = *(const f32x4*)(keys + c8);
    f32x4 b = *(const f32x4*)(keys + c8 + 4);
    u32x4 p;
    p.x = pack2f(a.x, a.y);
    p.y = pack2f(a.z, a.w);
    p.z = pack2f(b.x, b.y);
    p.w = pack2f(b.z, b.w);
    *(u32x4*)(keysbf + c8) = p;
  }
}

// ---------------- qterm[b][j] = b1[j] + sum_k query[b][k]*W1[k][j] ----------------
__global__ void qterm_kernel(const float* __restrict__ query, const float* __restrict__ W1,
                             const float* __restrict__ b1, float* __restrict__ qterm) {
  const int b = blockIdx.y;
  const int j = blockIdx.x * 64 + (threadIdx.x & 63);
  const int kq = threadIdx.x >> 6;  // 0..3
  __shared__ float part[4][64];
  const float* q = query + b * 1024 + kq * 256;
  const float* wp = W1 + (size_t)(kq * 256) * 1024 + j;
  float acc = 0.f;
#pragma unroll 8
  for (int k = 0; k < 256; ++k) acc += q[k] * wp[(size_t)k * 1024];
  part[kq][threadIdx.x & 63] = acc;
  __syncthreads();
  if (threadIdx.x < 64) {
    const int jj = blockIdx.x * 64 + threadIdx.x;
    qterm[b * 1024 + jj] = b1[jj] + part[0][threadIdx.x] + part[1][threadIdx.x] +
                           part[2][threadIdx.x] + part[3][threadIdx.x];
  }
}

// ---------------- fused GEMM + tanh + W2-reduce (v11: 256x256, 8 waves, wave tile 128x64) ----------------
// 512 thr / 8 waves (2 wm x 4 wn). BK=64, 16 k-tiles, grid 512 (128 rowgrps x 4 colgrps).
// LDS: A dbuf 2x32KB + B dbuf 2x32KB + Sred 4KB = 132KB -> 1 block/CU, 2 waves/SIMD.
// Bigger wave tile cuts LDS-read bytes/FLOP from 0.031 to 0.023 (measured LDS-BW-bound).
// One barrier per kt (o10's proven schedule): staged GLDs are a full LDS-bound compute
// phase (~2000 cy) old at the vmcnt(0) drain.

// stage a [256 rows][64 k] bf16 tile; XOR-fold in the global src, LDS dest linear.
// 8 waves x 4 calls x 8 rows = 256 rows; per call lane covers row w*32+i*8+(lane>>3).
#define STAGE_T(t_, src, Dd)                               \
  _Pragma("unroll") for (int i = 0; i < 4; ++i) {          \
    const int r = w * 32 + i * 8 + (lane >> 3);            \
    const int u = (lane & 7) ^ (r & 7);                    \
    GLD16((src) + (((size_t)r) << 10) + (t_) * 64 + u * 8, \
          (Dd) + w * 4096 + lane * 16 + i * 1024);         \
  }

#define V11_COMPUTE(Asrc, Bsrc)                                                          \
  _Pragma("unroll") for (int kk = 0; kk < 2; ++kk) {                                     \
    bf16x8 af[8], bfv[4];                                                                \
    _Pragma("unroll") for (int mf = 0; mf < 8; ++mf) {                                   \
      const int ra = wm * 128 + mf * 16 + c16;                                           \
      af[mf] = *(const bf16x8*)((Asrc) + ra * 128 + (((kk * 4 + q4) ^ (ra & 7)) << 4));  \
    }                                                                                    \
    _Pragma("unroll") for (int nf = 0; nf < 4; ++nf) {                                   \
      const int ca = wn * 64 + nf * 16 + c16;                                            \
      bfv[nf] = *(const bf16x8*)((Bsrc) + ca * 128 + (((kk * 4 + q4) ^ (ca & 7)) << 4)); \
    }                                                                                    \
    _Pragma("unroll") for (int nf = 0; nf < 4; ++nf)                                     \
        _Pragma("unroll") for (int mf = 0; mf < 8; ++mf) acc[mf][nf] =                   \
            MFMA16(af[mf], bfv[nf], acc[mf][nf]);                                        \
  }

#define V11_ITER(t_, Ac, Bc, An, Bn)                          \
  if ((t_) < 15) {                                            \
    STAGE_T((t_) + 1, gAbase, An);                            \
    STAGE_T((t_) + 1, gBbase, Bn);                            \
  }                                                           \
  SBAR0();                                                    \
  V11_COMPUTE(Ac, Bc);                                        \
  SBAR0();                                                    \
  asm volatile("s_waitcnt vmcnt(0) lgkmcnt(0)" ::: "memory"); \
  __builtin_amdgcn_s_barrier();

__global__ __launch_bounds__(512, 2) void gemm_score_v11(
    const unsigned short* __restrict__ keysbf, const unsigned short* __restrict__ W1kt,
    const float* __restrict__ qterm, const float* __restrict__ coverage,
    const float* __restrict__ W1, const float* __restrict__ W2,
    float* __restrict__ scores_part) {
  __shared__ __align__(16) unsigned char lds[135168];
  unsigned char* A0 = lds;               // 32KB
  unsigned char* A1 = lds + 32768;       // 32KB
  unsigned char* B0 = lds + 65536;       // 32KB
  unsigned char* B1 = lds + 98304;       // 32KB
  float* Sred = (float*)(lds + 131072);  // 8 x 128 f32

  const int tid = threadIdx.x;
  const int bid = blockIdx.x;  // 512
  // bijective XCD clustering: XCD x handles rowts [16x,16x+16), all 4 colgrps
  const int xcd = bid & 7;
  const int idx = bid >> 3;                 // 0..63
  const int rowt = xcd * 16 + (idx >> 2);   // 0..127
  const int colgrp = idx & 3;               // 0..3
  const int row0 = rowt * 256;
  const int col0 = colgrp * 256;
  const int b = row0 >> 11;
  const int w = tid >> 6;                   // 0..7
  const int wm = w >> 2, wn = w & 3;        // 2 x 4
  const int lane = tid & 63;
  const int c16 = lane & 15, q4 = lane >> 4;

  const unsigned short* gAbase = keysbf + ((size_t)row0 << 10);
  const unsigned short* gBbase = W1kt + ((size_t)col0 << 10);

  f32x4 acc[8][4];  // [mf][nf]
  const f32x4 zz = {0.f, 0.f, 0.f, 0.f};
#pragma unroll
  for (int mf = 0; mf < 8; ++mf)
#pragma unroll
    for (int nf = 0; nf < 4; ++nf) acc[mf][nf] = zz;

  // prologue
  STAGE_T(0, gAbase, A0);
  STAGE_T(0, gBbase, B0);
  asm volatile("s_waitcnt vmcnt(0)" ::: "memory");
  __builtin_amdgcn_s_barrier();

#pragma unroll 1
  for (int th = 0; th < 8; ++th) {
    const int t0 = th * 2, t1 = th * 2 + 1;
    V11_ITER(t0, A0, B0, A1, B1);
    V11_ITER(t1, A1, B1, A0, B0);
  }

  // ---- epilogue: v = acc + qterm + cov*W1c; p_part = sum_cols tanh(v)*W2 ----
  float covv[8][4];
#pragma unroll
  for (int mf = 0; mf < 8; ++mf)
#pragma unroll
    for (int r = 0; r < 4; ++r)
      covv[mf][r] = coverage[row0 + wm * 128 + mf * 16 + q4 * 4 + r];

  float p_part[8][4];
#pragma unroll
  for (int mf = 0; mf < 8; ++mf)
#pragma unroll
    for (int r = 0; r < 4; ++r) p_part[mf][r] = 0.f;

#pragma unroll
  for (int nf = 0; nf < 4; ++nf) {
    const int col = col0 + wn * 64 + nf * 16 + c16;
    const float qt = qterm[b * 1024 + col];
    const float w1c = W1[(size_t)2048 * 1024 + col];
    const float w2 = W2[col];
#pragma unroll
    for (int mf = 0; mf < 8; ++mf)
#pragma unroll
      for (int r = 0; r < 4; ++r) {
        float v = acc[mf][nf][r] + qt + covv[mf][r] * w1c;
        p_part[mf][r] += fast_tanh(v) * w2;
      }
  }

  // reduce over 16 col-lanes, then across the 4 wn-waves via Sred
#pragma unroll
  for (int mf = 0; mf < 8; ++mf)
#pragma unroll
    for (int r = 0; r < 4; ++r) {
      float p = p_part[mf][r];
      p += __shfl_xor(p, 1);
      p += __shfl_xor(p, 2);
      p += __shfl_xor(p, 4);
      p += __shfl_xor(p, 8);
      if (c16 == 0) Sred[w * 128 + mf * 16 + q4 * 4 + r] = p;
    }
  __syncthreads();
  if (tid < 256) {
    const int wmv = tid >> 7, rl = tid & 127;
    float s = Sred[(wmv * 4 + 0) * 128 + rl] + Sred[(wmv * 4 + 1) * 128 + rl] +
              Sred[(wmv * 4 + 2) * 128 + rl] + Sred[(wmv * 4 + 3) * 128 + rl];
    scores_part[(size_t)colgrp * 32768 + row0 + tid] = s;
  }
}

// ---------------- softmax over L per batch (sums 4 colgrp partials) ----------------
__global__ void softmax_kernel(const float* __restrict__ sp, float* __restrict__ att) {
  const int b = blockIdx.x;
  const int tid = threadIdx.x;
  float* a = att + b * 2048;
  __shared__ float red[4];
  float mx = -1e30f;
  for (int l = tid; l < 2048; l += 256) {
    float v = 0.f;
#pragma unroll
    for (int g = 0; g < 4; ++g) v += sp[(size_t)g * 32768 + b * 2048 + l];
    a[l] = v;
    mx = fmaxf(mx, v);
  }
#pragma unroll
  for (int o = 1; o < 64; o <<= 1) mx = fmaxf(mx, __shfl_xor(mx, o));
  if ((tid & 63) == 0) red[tid >> 6] = mx;
  __syncthreads();
  mx = fmaxf(fmaxf(red[0], red[1]), fmaxf(red[2], red[3]));
  __syncthreads();
  float sum = 0.f;
  for (int l = tid; l < 2048; l += 256) {
    float e = __expf(a[l] - mx);
    a[l] = e;
    sum += e;
  }
#pragma unroll
  for (int o = 1; o < 64; o <<= 1) sum += __shfl_xor(sum, o);
  if ((tid & 63) == 0) red[tid >> 6] = sum;
  __syncthreads();
  sum = red[0] + red[1] + red[2] + red[3];
  const float inv = 1.0f / sum;
  for (int l = tid; l < 2048; l += 256) a[l] *= inv;
}

// ---------------- ctx_part[sl][b][j] = sum over 128 rows of att*keysbf (bf16 reads) ----------------
__global__ void ctxpre_kernel(const unsigned short* __restrict__ keysbf,
                              const float* __restrict__ att, float* __restrict__ ctx_part) {
  const int b = blockIdx.x;     // 16
  const int sl = blockIdx.y;    // 16 slices of 128 rows
  const int tid = threadIdx.x;  // 256; thread covers cols tid*4..tid*4+3
  const float* ab = att + b * 2048 + sl * 128;
  const unsigned short* kb = keysbf + ((size_t)b * 2048 + sl * 128) * 1024 + tid * 4;
  f32x4 acc = {0.f, 0.f, 0.f, 0.f};
#pragma unroll 4
  for (int l = 0; l < 128; ++l) {
    u32x2 v = *(const u32x2*)(kb + (size_t)l * 1024);
    const float al = ab[l];
    acc.x += bfbits_to_f32(v.x & 0xFFFFu) * al;
    acc.y += bfbits_to_f32(v.x >> 16) * al;
    acc.z += bfbits_to_f32(v.y & 0xFFFFu) * al;
    acc.w += bfbits_to_f32(v.y >> 16) * al;
  }
  *(f32x4*)(ctx_part + ((size_t)(sl * 16 + b)) * 1024 + tid * 4) = acc;
}

// ---------------- ctx_pre[b][j] = sum_sl ctx_part[sl][b][j] ----------------
__global__ void ctxreduce_kernel(const float* __restrict__ ctx_part, float* __restrict__ ctx_pre) {
  const int i = blockIdx.x * 256 + threadIdx.x;
  const int b = i >> 10, j = i & 1023;
  float s = 0.f;
#pragma unroll
  for (int sl = 0; sl < 16; ++sl) s += ctx_part[((size_t)(sl * 16 + b)) * 1024 + j];
  ctx_pre[i] = s;
}

// ---------------- context[b][h] = sum_j ctx_pre[b][j] * Wr[j][h] ----------------
__global__ void context_kernel(const float* __restrict__ ctx_pre, const float* __restrict__ Wr,
                               float* __restrict__ out) {
  const int b = blockIdx.y;
  const int h = blockIdx.x * 64 + (threadIdx.x & 63);
  const int jq = threadIdx.x >> 6;
  __shared__ float part[4][64];
  const float* cp = ctx_pre + b * 1024 + jq * 256;
  const float* wp = Wr + (size_t)(jq * 256) * 512 + h;
  float acc = 0.f;
#pragma unroll 8
  for (int k = 0; k < 256; ++k) acc += cp[k] * wp[(size_t)k * 512];
  part[jq][threadIdx.x & 63] = acc;
  __syncthreads();
  if (threadIdx.x < 64)
    out[b * 512 + blockIdx.x * 64 + threadIdx.x] = part[0][threadIdx.x] + part[1][threadIdx.x] +
                                                   part[2][threadIdx.x] + part[3][threadIdx.x];
}

extern "C" void kernel_launch(void* const* d_in, const int* in_sizes, int n_in, void* d_out,
                              int out_size, void* d_ws, size_t ws_size, hipStream_t stream) {
  const float* query = (const float*)d_in[0];     // (16,1,1024)
  const float* keys = (const float*)d_in[1];      // (16,2048,1024)
  const float* coverage = (const float*)d_in[2];  // (16,2048,1)
  const float* W1 = (const float*)d_in[3];        // (2049,1024)
  const float* b1 = (const float*)d_in[4];        // (1024,)
  const float* W2 = (const float*)d_in[5];        // (1024,1)
  const float* Wr = (const float*)d_in[6];        // (1024,512)
  float* out = (float*)d_out;
  char* ws = (char*)d_ws;

  float* scores_part = (float*)ws;          // 4*32768 f32 = 512KB @ 0
  float* ctx_part = (float*)ws;             // 1MB, aliases scores_part (dead after softmax)
  float* ctx_pre = (float*)(ws + 1048576);  // 16384 f32
  float* qterm = (float*)(ws + 1114112);    // 16384 f32
  unsigned short* W1kt = (unsigned short*)(ws + 1179648);    // 1M bf16 (2MB)
  unsigned short* keysbf = (unsigned short*)(ws + 3276800);  // 32M bf16 (64MB)
  // ws >= 70.5MB proven in round 9 (fast path executed)

  float* context_out = out;     // 16*512
  float* att_out = out + 8192;  // 16*2048

  transpose_w1k<<<dim3(16, 16), dim3(256), 0, stream>>>(W1, W1kt);
  convert_keys<<<dim3(8192), dim3(256), 0, stream>>>(keys, keysbf);
  qterm_kernel<<<dim3(16, 16), dim3(256), 0, stream>>>(query, W1, b1, qterm);
  gemm_score_v11<<<dim3(512), dim3(512), 0, stream>>>(keysbf, W1kt, qterm, coverage, W1, W2,
                                                      scores_part);
  softmax_kernel<<<dim3(16), dim3(256), 0, stream>>>(scores_part, att_out);
  ctxpre_kernel<<<dim3(16, 16), dim3(256), 0, stream>>>(keysbf, att_out, ctx_part);
  ctxreduce_kernel<<<dim3(64), dim3(256), 0, stream>>>(ctx_part, ctx_pre);
  context_kernel<<<dim3(8, 16), dim3(256), 0, stream>>>(ctx_pre, Wr, context_out);
}

// Round 12
// 146.987 us; speedup vs baseline: 3.5467x; 1.1159x over previous
//
#include <hip/hip_runtime.h>
#include <hip/hip_bf16.h>
#include <stdint.h>

typedef short bf16x8 __attribute__((ext_vector_type(8)));
typedef float f32x4 __attribute__((ext_vector_type(4)));
typedef unsigned int u32x2 __attribute__((ext_vector_type(2)));
typedef unsigned int u32x4 __attribute__((ext_vector_type(4)));

__device__ __forceinline__ uint32_t pack2f(float lo, float hi) {
  union { __hip_bfloat162 h; uint32_t u; } c;
  c.h.x = __float2bfloat16(lo);
  c.h.y = __float2bfloat16(hi);
  return c.u;
}

__device__ __forceinline__ unsigned short f32_to_bf16(float f) {
  union { __hip_bfloat16 h; unsigned short u; } c;
  c.h = __float2bfloat16(f);
  return c.u;
}

__device__ __forceinline__ float bfbits_to_f32(uint32_t hi16) {
  union { uint32_t u; float f; } c;
  c.u = hi16 << 16;
  return c.f;
}

__device__ __forceinline__ float fast_tanh(float x) {
  float e = __builtin_amdgcn_exp2f(x * 2.8853900817779268f);
  return 1.0f - 2.0f * __builtin_amdgcn_rcpf(e + 1.0f);
}

#define GLD16(g, l)                                                                    \
  __builtin_amdgcn_global_load_lds((const __attribute__((address_space(1))) void*)(g), \
                                   (__attribute__((address_space(3))) void*)(l), 16, 0, 0)

#define MFMA16(a, b, c) __builtin_amdgcn_mfma_f32_16x16x32_bf16(a, b, c, 0, 0, 0)
#define SBAR0() __builtin_amdgcn_sched_barrier(0)

// ---------------- fused prep: convert keys->bf16 | transpose W1k | qterm ----------------
__global__ void prep_kernel(const float* __restrict__ keys, unsigned short* __restrict__ keysbf,
                            const float* __restrict__ W1, unsigned short* __restrict__ W1kt,
                            const float* __restrict__ query, const float* __restrict__ b1,
                            float* __restrict__ qterm) {
  __shared__ __align__(16) unsigned char smem[16896];
  const int bid = blockIdx.x;
  const int t = threadIdx.x;
  if (bid < 8192) {
    // convert keys -> bf16 row-major
#pragma unroll
    for (int it = 0; it < 2; ++it) {
      const size_t c8 = ((size_t)bid * 512 + it * 256 + t) * 8;
      f32x4 a = *(const f32x4*)(keys + c8);
      f32x4 b = *(const f32x4*)(keys + c8 + 4);
      u32x4 p;
      p.x = pack2f(a.x, a.y);
      p.y = pack2f(a.z, a.w);
      p.z = pack2f(b.x, b.y);
      p.w = pack2f(b.z, b.w);
      *(u32x4*)(keysbf + c8) = p;
    }
  } else if (bid < 8448) {
    // W1kt[j][k] = bf16(W1[1024+k][j])
    float (*tt)[65] = (float(*)[65])smem;
    const int tb = bid - 8192;
    const int kb = (tb & 15) * 64;
    const int jb = (tb >> 4) * 64;
    const int c = t & 63;
    const int r = t >> 6;
#pragma unroll
    for (int i = 0; i < 16; ++i) {
      const int k = i * 4 + r;
      tt[k][c] = W1[(size_t)(1024 + kb + k) * 1024 + (jb + c)];
    }
    __syncthreads();
#pragma unroll
    for (int i = 0; i < 16; ++i) {
      const int j = i * 4 + r;
      W1kt[(size_t)(jb + j) * 1024 + (kb + c)] = f32_to_bf16(tt[c][j]);
    }
  } else {
    // qterm[b][j] = b1[j] + sum_k query[b][k]*W1[k][j]
    float (*part)[64] = (float(*)[64])smem;
    const int q = bid - 8448;
    const int b = q >> 4;
    const int j = (q & 15) * 64 + (t & 63);
    const int kq = t >> 6;
    const float* qp = query + b * 1024 + kq * 256;
    const float* wp = W1 + (size_t)(kq * 256) * 1024 + j;
    float acc = 0.f;
#pragma unroll 8
    for (int k = 0; k < 256; ++k) acc += qp[k] * wp[(size_t)k * 1024];
    part[kq][t & 63] = acc;
    __syncthreads();
    if (t < 64) {
      const int jj = (q & 15) * 64 + t;
      qterm[b * 1024 + jj] = b1[jj] + part[0][t] + part[1][t] + part[2][t] + part[3][t];
    }
  }
}

// ---------------- fused GEMM + tanh + W2-reduce (v12: triple-buffer counted vmcnt) ----------------
// 512 thr / 8 waves (2 wm x 4 wn, wave tile 128x64). Tile 256x256, BK=32, 32 k-steps.
// 3 LDS buffers P0..P2 (A 16KB + B 16KB each = 96KB + Sred). Per iter t:
//   s_waitcnt vmcnt(4)   (S(t) done; S(t+1)'s 4 ops stay in flight ACROSS the barrier)
//   s_barrier
//   issue S(t+2) -> P[(t+2)%3]   (== buffer compute(t-1) vacated before this barrier)
//   setprio(1); 32 MFMA from P[t%3]; setprio(0)
// Stage latency budget: issue(iter t) -> needed(iter t+2) = 2 compute phases (~800cy) >> L2.
// LDS layout per buf: A row r: 64B/row, 16B slot s holds k-group (s ^ ((r>>1)&3)) -> 2-way
// max bank aliasing on both ds_read_b128 and the linear GLD writes (free per m136).

#define V12_STAGE(kt_, P)                                                           \
  _Pragma("unroll") for (int i = 0; i < 2; ++i) {                                   \
    const int r = i * 128 + w * 16 + (lane >> 2);                                   \
    const int u = (lane & 3) ^ ((r >> 1) & 3);                                      \
    GLD16(keysbf + (size_t)(row0 + r) * 1024 + (kt_) * 32 + u * 8,                  \
          (P) + i * 8192 + w * 1024 + lane * 16);                                   \
    GLD16(W1kt + (size_t)(col0 + r) * 1024 + (kt_) * 32 + u * 8,                    \
          (P) + 16384 + i * 8192 + w * 1024 + lane * 16);                           \
  }

#define V12_COMPUTE(P)                                                              \
  {                                                                                 \
    bf16x8 af[8], bfv[4];                                                           \
    _Pragma("unroll") for (int mf = 0; mf < 8; ++mf) {                              \
      const int ra = wm * 128 + mf * 16 + c16;                                      \
      af[mf] = *(const bf16x8*)((P) + ra * 64 + ((q4 ^ ((ra >> 1) & 3)) << 4));     \
    }                                                                               \
    _Pragma("unroll") for (int nf = 0; nf < 4; ++nf) {                              \
      const int ca = wn * 64 + nf * 16 + c16;                                       \
      bfv[nf] =                                                                     \
          *(const bf16x8*)((P) + 16384 + ca * 64 + ((q4 ^ ((ca >> 1) & 3)) << 4));  \
    }                                                                               \
    __builtin_amdgcn_s_setprio(1);                                                  \
    _Pragma("unroll") for (int nf = 0; nf < 4; ++nf)                                \
        _Pragma("unroll") for (int mf = 0; mf < 8; ++mf) acc[mf][nf] =              \
            MFMA16(af[mf], bfv[nf], acc[mf][nf]);                                   \
    __builtin_amdgcn_s_setprio(0);                                                  \
  }

#define V12_ITER(ts_, Pc, Ps)                             \
  asm volatile("s_waitcnt vmcnt(4)" ::: "memory");        \
  __builtin_amdgcn_s_barrier();                           \
  SBAR0();                                                \
  V12_STAGE(ts_, Ps);                                     \
  V12_COMPUTE(Pc);

__global__ __launch_bounds__(512, 2) void gemm_score_v12(
    const unsigned short* __restrict__ keysbf, const unsigned short* __restrict__ W1kt,
    const float* __restrict__ qterm, const float* __restrict__ coverage,
    const float* __restrict__ W1, const float* __restrict__ W2,
    float* __restrict__ scores_part) {
  __shared__ __align__(16) unsigned char lds[102400];
  unsigned char* P0 = lds;               // A 16KB + B 16KB
  unsigned char* P1 = lds + 32768;
  unsigned char* P2 = lds + 65536;
  float* Sred = (float*)(lds + 98304);   // 8 x 128 f32

  const int tid = threadIdx.x;
  const int bid = blockIdx.x;  // 512
  // bijective XCD clustering
  const int xcd = bid & 7;
  const int idx = bid >> 3;                // 0..63
  const int rowt = xcd * 16 + (idx >> 2);  // 0..127
  const int colgrp = idx & 3;              // 0..3
  const int row0 = rowt * 256;
  const int col0 = colgrp * 256;
  const int b = row0 >> 11;
  const int w = tid >> 6;             // 0..7
  const int wm = w >> 2, wn = w & 3;  // 2 x 4
  const int lane = tid & 63;
  const int c16 = lane & 15, q4 = lane >> 4;

  f32x4 acc[8][4];  // [mf][nf]
  const f32x4 zz = {0.f, 0.f, 0.f, 0.f};
#pragma unroll
  for (int mf = 0; mf < 8; ++mf)
#pragma unroll
    for (int nf = 0; nf < 4; ++nf) acc[mf][nf] = zz;

  // prologue: S(0)->P0 (oldest), S(1)->P1
  V12_STAGE(0, P0);
  V12_STAGE(1, P1);

#pragma unroll 1
  for (int tb = 0; tb < 30; tb += 3) {
    V12_ITER(tb + 2, P0, P2);
    V12_ITER(tb + 3, P1, P0);
    V12_ITER(tb + 4, P2, P1);
  }
  // t=30: compute P0 (S(31) still in flight), t=31: compute P1
  asm volatile("s_waitcnt vmcnt(4)" ::: "memory");
  __builtin_amdgcn_s_barrier();
  SBAR0();
  V12_COMPUTE(P0);
  asm volatile("s_waitcnt vmcnt(0)" ::: "memory");
  __builtin_amdgcn_s_barrier();
  SBAR0();
  V12_COMPUTE(P1);

  // ---- epilogue: v = acc + qterm + cov*W1c; p_part = sum_cols tanh(v)*W2 ----
  float covv[8][4];
#pragma unroll
  for (int mf = 0; mf < 8; ++mf)
#pragma unroll
    for (int r = 0; r < 4; ++r)
      covv[mf][r] = coverage[row0 + wm * 128 + mf * 16 + q4 * 4 + r];

  float p_part[8][4];
#pragma unroll
  for (int mf = 0; mf < 8; ++mf)
#pragma unroll
    for (int r = 0; r < 4; ++r) p_part[mf][r] = 0.f;

#pragma unroll
  for (int nf = 0; nf < 4; ++nf) {
    const int col = col0 + wn * 64 + nf * 16 + c16;
    const float qt = qterm[b * 1024 + col];
    const float w1c = W1[(size_t)2048 * 1024 + col];
    const float w2 = W2[col];
#pragma unroll
    for (int mf = 0; mf < 8; ++mf)
#pragma unroll
      for (int r = 0; r < 4; ++r) {
        float v = acc[mf][nf][r] + qt + covv[mf][r] * w1c;
        p_part[mf][r] += fast_tanh(v) * w2;
      }
  }

  // reduce over 16 col-lanes, then across the 4 wn-waves via Sred
#pragma unroll
  for (int mf = 0; mf < 8; ++mf)
#pragma unroll
    for (int r = 0; r < 4; ++r) {
      float p = p_part[mf][r];
      p += __shfl_xor(p, 1);
      p += __shfl_xor(p, 2);
      p += __shfl_xor(p, 4);
      p += __shfl_xor(p, 8);
      if (c16 == 0) Sred[w * 128 + mf * 16 + q4 * 4 + r] = p;
    }
  __syncthreads();
  if (tid < 256) {
    const int wmv = tid >> 7, rl = tid & 127;
    float s = Sred[(wmv * 4 + 0) * 128 + rl] + Sred[(wmv * 4 + 1) * 128 + rl] +
              Sred[(wmv * 4 + 2) * 128 + rl] + Sred[(wmv * 4 + 3) * 128 + rl];
    scores_part[(size_t)colgrp * 32768 + row0 + tid] = s;
  }
}

// ---------------- softmax over L per batch (sums 4 colgrp partials) ----------------
__global__ void softmax_kernel(const float* __restrict__ sp, float* __restrict__ att) {
  const int b = blockIdx.x;
  const int tid = threadIdx.x;
  float* a = att + b * 2048;
  __shared__ float red[4];
  float mx = -1e30f;
  for (int l = tid; l < 2048; l += 256) {
    float v = 0.f;
#pragma unroll
    for (int g = 0; g < 4; ++g) v += sp[(size_t)g * 32768 + b * 2048 + l];
    a[l] = v;
    mx = fmaxf(mx, v);
  }
#pragma unroll
  for (int o = 1; o < 64; o <<= 1) mx = fmaxf(mx, __shfl_xor(mx, o));
  if ((tid & 63) == 0) red[tid >> 6] = mx;
  __syncthreads();
  mx = fmaxf(fmaxf(red[0], red[1]), fmaxf(red[2], red[3]));
  __syncthreads();
  float sum = 0.f;
  for (int l = tid; l < 2048; l += 256) {
    float e = __expf(a[l] - mx);
    a[l] = e;
    sum += e;
  }
#pragma unroll
  for (int o = 1; o < 64; o <<= 1) sum += __shfl_xor(sum, o);
  if ((tid & 63) == 0) red[tid >> 6] = sum;
  __syncthreads();
  sum = red[0] + red[1] + red[2] + red[3];
  const float inv = 1.0f / sum;
  for (int l = tid; l < 2048; l += 256) a[l] *= inv;
}

// ---------------- ctx_part[sl][b][j] = sum over 128 rows of att*keysbf (bf16 reads) ----------------
__global__ void ctxpre_kernel(const unsigned short* __restrict__ keysbf,
                              const float* __restrict__ att, float* __restrict__ ctx_part) {
  const int b = blockIdx.x;     // 16
  const int sl = blockIdx.y;    // 16 slices of 128 rows
  const int tid = threadIdx.x;  // 256; thread covers cols tid*4..tid*4+3
  const float* ab = att + b * 2048 + sl * 128;
  const unsigned short* kb = keysbf + ((size_t)b * 2048 + sl * 128) * 1024 + tid * 4;
  f32x4 acc = {0.f, 0.f, 0.f, 0.f};
#pragma unroll 4
  for (int l = 0; l < 128; ++l) {
    u32x2 v = *(const u32x2*)(kb + (size_t)l * 1024);
    const float al = ab[l];
    acc.x += bfbits_to_f32(v.x & 0xFFFFu) * al;
    acc.y += bfbits_to_f32(v.x >> 16) * al;
    acc.z += bfbits_to_f32(v.y & 0xFFFFu) * al;
    acc.w += bfbits_to_f32(v.y >> 16) * al;
  }
  *(f32x4*)(ctx_part + ((size_t)(sl * 16 + b)) * 1024 + tid * 4) = acc;
}

// ---------------- fused: ctx_pre reduce (into LDS) + context matmul ----------------
__global__ void ctx2_kernel(const float* __restrict__ ctx_part, const float* __restrict__ Wr,
                            float* __restrict__ out) {
  __shared__ float cpre[1024];
  __shared__ float part[4][64];
  const int hb = blockIdx.x;  // 8
  const int b = blockIdx.y;   // 16
  const int t = threadIdx.x;  // 256
#pragma unroll
  for (int jj = 0; jj < 4; ++jj) {
    const int j = jj * 256 + t;
    float s = 0.f;
#pragma unroll
    for (int sl = 0; sl < 16; ++sl) s += ctx_part[((size_t)(sl * 16 + b)) * 1024 + j];
    cpre[j] = s;
  }
  __syncthreads();
  const int h = hb * 64 + (t & 63);
  const int jq = t >> 6;
  const float* wp = Wr + (size_t)(jq * 256) * 512 + h;
  float acc = 0.f;
#pragma unroll 8
  for (int k = 0; k < 256; ++k) acc += cpre[jq * 256 + k] * wp[(size_t)k * 512];
  part[jq][t & 63] = acc;
  __syncthreads();
  if (t < 64)
    out[b * 512 + hb * 64 + t] = part[0][t] + part[1][t] + part[2][t] + part[3][t];
}

extern "C" void kernel_launch(void* const* d_in, const int* in_sizes, int n_in, void* d_out,
                              int out_size, void* d_ws, size_t ws_size, hipStream_t stream) {
  const float* query = (const float*)d_in[0];     // (16,1,1024)
  const float* keys = (const float*)d_in[1];      // (16,2048,1024)
  const float* coverage = (const float*)d_in[2];  // (16,2048,1)
  const float* W1 = (const float*)d_in[3];        // (2049,1024)
  const float* b1 = (const float*)d_in[4];        // (1024,)
  const float* W2 = (const float*)d_in[5];        // (1024,1)
  const float* Wr = (const float*)d_in[6];        // (1024,512)
  float* out = (float*)d_out;
  char* ws = (char*)d_ws;

  float* scores_part = (float*)ws;          // 4*32768 f32 = 512KB @ 0
  float* ctx_part = (float*)ws;             // 1MB, aliases scores_part (dead after softmax)
  float* qterm = (float*)(ws + 1114112);    // 16384 f32
  unsigned short* W1kt = (unsigned short*)(ws + 1179648);    // 1M bf16 (2MB)
  unsigned short* keysbf = (unsigned short*)(ws + 3276800);  // 32M bf16 (64MB)
  // ws >= 70.5MB proven in round 9 (fast path executed)

  float* context_out = out;     // 16*512
  float* att_out = out + 8192;  // 16*2048

  prep_kernel<<<dim3(8704), dim3(256), 0, stream>>>(keys, keysbf, W1, W1kt, query, b1, qterm);
  gemm_score_v12<<<dim3(512), dim3(512), 0, stream>>>(keysbf, W1kt, qterm, coverage, W1, W2,
                                                      scores_part);
  softmax_kernel<<<dim3(16), dim3(256), 0, stream>>>(scores_part, att_out);
  ctxpre_kernel<<<dim3(16, 16), dim3(256), 0, stream>>>(keysbf, att_out, ctx_part);
  ctx2_kernel<<<dim3(8, 16), dim3(256), 0, stream>>>(ctx_part, Wr, context_out);
}